// Round 1
// baseline (4880.623 us; speedup 1.0000x reference)
//
#include <hip/hip_runtime.h>
#include <cstdint>
#include <cstddef>

// Problem constants (reference: T,B,H_IN,H_HID = 2048,64,256,256)
#define T_LEN 2048
#define B_N   64
#define H_INP 256
#define H_HID 256
#define G3    768              // 3*H_HID (gates r,z,n)
#define M_ROWS (T_LEN * B_N)   // 131072

typedef _Float16 f16;
typedef _Float16 f16x2 __attribute__((ext_vector_type(2)));
typedef _Float16 f16x8 __attribute__((ext_vector_type(8)));
typedef float    f32x4 __attribute__((ext_vector_type(4)));

static __device__ __forceinline__ float fdot2f(uint32_t a, uint32_t b, float c) {
#if __has_builtin(__builtin_amdgcn_fdot2)
  return __builtin_amdgcn_fdot2(__builtin_bit_cast(f16x2, a),
                                __builtin_bit_cast(f16x2, b), c, false);
#else
  f16x2 av = __builtin_bit_cast(f16x2, a);
  f16x2 bv = __builtin_bit_cast(f16x2, b);
  return c + (float)av.x * (float)bv.x + (float)av.y * (float)bv.y;
#endif
}

// ---------------------------------------------------------------- zero d_out
__global__ void k_zero(float4* __restrict__ p, int n4) {
  int i = blockIdx.x * blockDim.x + threadIdx.x;
  int stride = gridDim.x * blockDim.x;
  float4 z; z.x = z.y = z.z = z.w = 0.f;
  for (; i < n4; i += stride) p[i] = z;
}

// ------------------------------------------------------------- f32 -> f16
__global__ void k_cvt(const float2* __restrict__ s, f16x2* __restrict__ d, int n2) {
  int i = blockIdx.x * blockDim.x + threadIdx.x;
  int stride = gridDim.x * blockDim.x;
  for (; i < n2; i += stride) {
    float2 v = s[i];
    f16x2 p; p.x = (f16)v.x; p.y = (f16)v.y;
    d[i] = p;
  }
}

// ------------------------------------------------- mask bookkeeping (1 block)
// Produces: lens[b], tidx[b][k] = t of k-th valid step of column b,
//           inv[r] = flat index j (=t*B+b) of the r-th true mask position,
//           ntru[0] = total number of true positions.
__global__ __launch_bounds__(1024) void k_prep(const int* __restrict__ mask,
                                               int* __restrict__ tidx,
                                               int* __restrict__ lens,
                                               int* __restrict__ inv,
                                               int* __restrict__ ntru) {
  const int tid = threadIdx.x;
  const int c = tid >> 6;   // 16 chunks of 128 t's
  const int b = tid & 63;
  __shared__ int cntA[16][64];
  __shared__ int offA[16][64];
  __shared__ int wsum[16];

  // per-column counts over t-chunks
  const int tbase = c * 128;
  int cnt = 0;
  for (int t = 0; t < 128; ++t) cnt += (mask[(tbase + t) * B_N + b] != 0);
  cntA[c][b] = cnt;
  __syncthreads();
  if (tid < 64) {
    int run = 0;
    for (int cc = 0; cc < 16; ++cc) { offA[cc][tid] = run; run += cntA[cc][tid]; }
    lens[tid] = run;
  }
  __syncthreads();
  {
    int off = offA[c][b];
    for (int t = 0; t < 128; ++t)
      if (mask[(tbase + t) * B_N + b] != 0) { tidx[b * T_LEN + off] = tbase + t; ++off; }
  }

  // flat exclusive ranks -> inverse permutation
  const int fbase = tid * 128;  // 1024*128 = 131072 = T*B
  int cf = 0;
  for (int i = 0; i < 128; ++i) cf += (mask[fbase + i] != 0);
  int incl = cf;
  for (int d = 1; d < 64; d <<= 1) {
    int v = __shfl_up(incl, d, 64);
    if ((tid & 63) >= d) incl += v;
  }
  if ((tid & 63) == 63) wsum[tid >> 6] = incl;
  __syncthreads();
  if (tid == 0) {
    int run = 0;
    for (int w = 0; w < 16; ++w) { int s = wsum[w]; wsum[w] = run; run += s; }
    ntru[0] = run;
  }
  __syncthreads();
  int r = incl - cf + wsum[tid >> 6];
  for (int i = 0; i < 128; ++i)
    if (mask[fbase + i] != 0) { inv[r] = fbase + i; ++r; }
}

// ------------------------------------------- gi = X @ W_ih^T + b_ih (f16 MFMA)
// M=131072, K=256, N=768. No LDS: A and B fragments load 16B contiguous
// directly from row-major X[m][k] and W[n][k].
__global__ __launch_bounds__(256) void k_gemm(const f16* __restrict__ X,
                                              const f16* __restrict__ W,
                                              const float* __restrict__ bias,
                                              f16* __restrict__ GI) {
  const int lane = threadIdx.x & 63;
  const int wave = threadIdx.x >> 6;
  const int m0 = blockIdx.x * 64 + wave * 16;
  const int n0 = blockIdx.y * 64;
  const int idx16 = lane & 15;        // m (A) / n (B) within 16-tile
  const int kofs  = (lane >> 4) * 8;  // k chunk of 8

  const f16* ap  = X + (size_t)(m0 + idx16) * H_INP + kofs;
  const f16* bp0 = W + (size_t)(n0 + idx16) * H_INP + kofs;

  f32x4 acc[4] = { {0,0,0,0}, {0,0,0,0}, {0,0,0,0}, {0,0,0,0} };
#pragma unroll
  for (int kt = 0; kt < 8; ++kt) {
    f16x8 a = *(const f16x8*)(ap + kt * 32);
#pragma unroll
    for (int nt = 0; nt < 4; ++nt) {
      f16x8 bb = *(const f16x8*)(bp0 + (size_t)nt * 16 * H_INP + kt * 32);
      acc[nt] = __builtin_amdgcn_mfma_f32_16x16x32_f16(a, bb, acc[nt], 0, 0, 0);
    }
  }
  // C/D layout: row = (lane>>4)*4 + reg, col = lane&15
  const int mbase = m0 + (lane >> 4) * 4;
#pragma unroll
  for (int nt = 0; nt < 4; ++nt) {
    const int col = n0 + nt * 16 + idx16;
    const float bv = bias[col];
#pragma unroll
    for (int r = 0; r < 4; ++r)
      GI[(size_t)(mbase + r) * G3 + col] = (f16)(acc[nt][r] + bv);
  }
}

// -------------------------------------------------- GRU scan, 1 column / block
// 768 threads; thread j holds W_hh row j (256 f16 = 128 dwords) in VGPRs.
// h broadcast lane-uniformly via v_readlane + v_dot2_f32_f16.
__global__ __launch_bounds__(768) void k_scan(const f16* __restrict__ Whh,
                                              const f16* __restrict__ GI,
                                              const float* __restrict__ h0,
                                              const float* __restrict__ bhh,
                                              const int* __restrict__ tidx,
                                              const int* __restrict__ lens,
                                              const int* __restrict__ inv,
                                              const int* __restrict__ ntru,
                                              float* __restrict__ out) {
  const int b = blockIdx.x;
  const int j = threadIdx.x;
  const int lane = j & 63;

  __shared__ uint32_t hpk[128];  // h as 128 packed f16 pairs
  __shared__ float ghs[G3];

  uint32_t w[128];
  {
    const uint4* wp = (const uint4*)(Whh + (size_t)j * H_HID);
#pragma unroll
    for (int i = 0; i < 32; ++i) {
      uint4 v = wp[i];
      w[4*i+0] = v.x; w[4*i+1] = v.y; w[4*i+2] = v.z; w[4*i+3] = v.w;
    }
  }
  const float bias = bhh[j];
  float h_reg = 0.f;
  if (j < H_HID) h_reg = h0[b * H_HID + j];
  if (j < 128) {
    float2 hv = ((const float2*)(h0 + b * H_HID))[j];
    f16x2 p; p.x = (f16)hv.x; p.y = (f16)hv.y;
    hpk[j] = __builtin_bit_cast(uint32_t, p);
  }
  const int L  = lens[b];
  const int Nt = ntru[0];
  __syncthreads();

  for (int k = 0; k < L; ++k) {
    const int t = tidx[b * T_LEN + k];
    const size_t gbase = ((size_t)t * B_N + b) * G3;
    float gi0 = 0.f, gi1 = 0.f, gi2 = 0.f;
    if (j < H_HID) {
      gi0 = (float)GI[gbase + j];
      gi1 = (float)GI[gbase + H_HID + j];
      gi2 = (float)GI[gbase + 2 * H_HID + j];
    }
    uint32_t hv0 = hpk[lane];
    uint32_t hv1 = hpk[64 + lane];
    float acc0 = bias, acc1 = 0.f;
#pragma unroll
    for (int i = 0; i < 64; ++i) {
      int s = __builtin_amdgcn_readlane((int)hv0, i);
      acc0 = fdot2f(w[i], (uint32_t)s, acc0);
    }
#pragma unroll
    for (int i = 0; i < 64; ++i) {
      int s = __builtin_amdgcn_readlane((int)hv1, i);
      acc1 = fdot2f(w[64 + i], (uint32_t)s, acc1);
    }
    const float gh = acc0 + acc1;
    ghs[j] = gh;
    __syncthreads();
    if (j < H_HID) {
      const float ghr = gh;
      const float ghz = ghs[H_HID + j];
      const float ghn = ghs[2 * H_HID + j];
      const float r = 1.f / (1.f + __expf(-(gi0 + ghr)));
      const float z = 1.f / (1.f + __expf(-(gi1 + ghz)));
      const float n = tanhf(gi2 + r * ghn);
      const float hn = (1.f - z) * n + z * h_reg;
      h_reg = hn;
      const long pr = (long)k * B_N + b;
      if (pr < Nt) out[(size_t)inv[pr] * H_HID + j] = hn;
      ((f16*)hpk)[j] = (f16)hn;   // repack h for next step's matvec
    }
    __syncthreads();
  }
  if (j < H_HID) out[(size_t)M_ROWS * H_HID + (size_t)b * H_HID + j] = h_reg;
}

// ---------------------------------------------------------------------------
extern "C" void kernel_launch(void* const* d_in, const int* in_sizes, int n_in,
                              void* d_out, int out_size, void* d_ws, size_t ws_size,
                              hipStream_t stream) {
  const float* x    = (const float*)d_in[0];
  const float* h0   = (const float*)d_in[1];
  const int*   mask = (const int*)d_in[2];
  const float* wih  = (const float*)d_in[3];
  const float* whh  = (const float*)d_in[4];
  const float* bih  = (const float*)d_in[5];
  const float* bhh  = (const float*)d_in[6];
  float* out = (float*)d_out;

  // workspace layout (needs ~258 MiB)
  char* ws = (char*)d_ws;
  f16* X16   = (f16*)(ws + 0);            //  67,108,864 B
  f16* Wih16 = (f16*)(ws + 67108864);     //     393,216 B
  f16* Whh16 = (f16*)(ws + 67502080);     //     393,216 B
  f16* GI    = (f16*)(ws + 67895296);     // 201,326,592 B
  int* tidx  = (int*)(ws + 269221888);    //     524,288 B
  int* inv   = (int*)(ws + 269746176);    //     524,288 B
  int* lens  = (int*)(ws + 270270464);    //         256 B
  int* ntru  = (int*)(ws + 270270720);    //           4 B

  hipLaunchKernelGGL(k_zero, dim3(4096), dim3(256), 0, stream,
                     (float4*)d_out, out_size / 4);
  hipLaunchKernelGGL(k_prep, dim3(1), dim3(1024), 0, stream,
                     mask, tidx, lens, inv, ntru);
  hipLaunchKernelGGL(k_cvt, dim3(4096), dim3(256), 0, stream,
                     (const float2*)x, (f16x2*)X16, M_ROWS * H_INP / 2);
  hipLaunchKernelGGL(k_cvt, dim3(96), dim3(256), 0, stream,
                     (const float2*)wih, (f16x2*)Wih16, G3 * H_INP / 2);
  hipLaunchKernelGGL(k_cvt, dim3(96), dim3(256), 0, stream,
                     (const float2*)whh, (f16x2*)Whh16, G3 * H_INP / 2);
  hipLaunchKernelGGL(k_gemm, dim3(M_ROWS / 64, G3 / 64), dim3(256), 0, stream,
                     X16, Wih16, bih, GI);
  hipLaunchKernelGGL(k_scan, dim3(B_N), dim3(768), 0, stream,
                     Whh16, GI, h0, bhh, tidx, lens, inv, ntru, out);
}

// Round 2
// 3220.310 us; speedup vs baseline: 1.5156x; 1.5156x over previous
//
#include <hip/hip_runtime.h>
#include <cstdint>
#include <cstddef>

// Problem constants (reference: T,B,H_IN,H_HID = 2048,64,256,256)
#define T_LEN 2048
#define B_N   64
#define H_INP 256
#define H_HID 256
#define G3    768              // 3*H_HID (gates r,z,n)
#define M_ROWS (T_LEN * B_N)   // 131072
#define SCH   16               // scan steps per LDS chunk

typedef _Float16 f16;
typedef _Float16 f16x2 __attribute__((ext_vector_type(2)));
typedef _Float16 f16x8 __attribute__((ext_vector_type(8)));
typedef float    f32x4 __attribute__((ext_vector_type(4)));

// ---------------------------------------------------------------- zero d_out
__global__ void k_zero(float4* __restrict__ p, int n4) {
  int i = blockIdx.x * blockDim.x + threadIdx.x;
  int stride = gridDim.x * blockDim.x;
  float4 z; z.x = z.y = z.z = z.w = 0.f;
  for (; i < n4; i += stride) p[i] = z;
}

// ------------------------------------------------------------- f32 -> f16
__global__ void k_cvt(const float2* __restrict__ s, f16x2* __restrict__ d, int n2) {
  int i = blockIdx.x * blockDim.x + threadIdx.x;
  int stride = gridDim.x * blockDim.x;
  for (; i < n2; i += stride) {
    float2 v = s[i];
    f16x2 p; p.x = (f16)v.x; p.y = (f16)v.y;
    d[i] = p;
  }
}

// ---------------------------------------------- per-column pack: tidx, lens
// one wave per column b: ballot-scan over t
__global__ __launch_bounds__(64) void k_prep_col(const int* __restrict__ mask,
                                                 unsigned short* __restrict__ tidx,
                                                 int* __restrict__ lens) {
  const int b = blockIdx.x;
  const int lane = threadIdx.x;
  unsigned short* tp = tidx + b * T_LEN;
  int base = 0;
  for (int c = 0; c < T_LEN / 64; ++c) {
    int t = c * 64 + lane;
    bool m = mask[t * B_N + b] != 0;
    unsigned long long bal = __ballot(m);
    int pc = __popcll(bal & ((1ull << lane) - 1ull));
    if (m) tp[base + pc] = (unsigned short)t;
    base += __popcll(bal);
  }
  if (lane == 0) lens[b] = base;
}

// --------------------------------------------------- per-row true counts
__global__ __launch_bounds__(256) void k_rowcnt(const int* __restrict__ mask,
                                                int* __restrict__ rowcnt) {
  int g = blockIdx.x * 256 + threadIdx.x;
  int t = g >> 6, lane = g & 63;
  bool m = mask[t * B_N + lane] != 0;
  unsigned long long bal = __ballot(m);
  if (lane == 0) rowcnt[t] = __popcll(bal);
}

// ------------------------------------------- exclusive prefix of rowcnt[2048]
__global__ __launch_bounds__(512) void k_rowpref(const int* __restrict__ rowcnt,
                                                 int* __restrict__ rowpref,
                                                 int* __restrict__ ntru) {
  const int tid = threadIdx.x;
  const int lane = tid & 63, w = tid >> 6;
  int4 v = ((const int4*)rowcnt)[tid];
  int s = v.x + v.y + v.z + v.w;
  int incl = s;
  for (int d = 1; d < 64; d <<= 1) {
    int t = __shfl_up(incl, d, 64);
    if (lane >= d) incl += t;
  }
  __shared__ int wt[8], wo[8];
  if (lane == 63) wt[w] = incl;
  __syncthreads();
  if (tid == 0) {
    int run = 0;
    for (int i = 0; i < 8; ++i) { wo[i] = run; run += wt[i]; }
    ntru[0] = run;
  }
  __syncthreads();
  int base = wo[w] + incl - s;
  int4 o; o.x = base; o.y = base + v.x; o.z = o.y + v.y; o.w = o.z + v.z;
  ((int4*)rowpref)[tid] = o;
}

// --------------------------------------------------- inverse permutation
__global__ __launch_bounds__(256) void k_inv(const int* __restrict__ mask,
                                             const int* __restrict__ rowpref,
                                             int* __restrict__ inv) {
  int g = blockIdx.x * 256 + threadIdx.x;
  int t = g >> 6, lane = g & 63;
  bool m = mask[t * B_N + lane] != 0;
  unsigned long long bal = __ballot(m);
  int r = rowpref[t] + __popcll(bal & ((1ull << lane) - 1ull));
  if (m) inv[r] = t * B_N + lane;
}

// ------------------------------------------- gi = X @ W_ih^T + b_ih (f16 MFMA)
__global__ __launch_bounds__(256) void k_gemm(const f16* __restrict__ X,
                                              const f16* __restrict__ W,
                                              const float* __restrict__ bias,
                                              f16* __restrict__ GI) {
  const int lane = threadIdx.x & 63;
  const int wave = threadIdx.x >> 6;
  const int m0 = blockIdx.x * 64 + wave * 16;
  const int n0 = blockIdx.y * 64;
  const int idx16 = lane & 15;
  const int kofs  = (lane >> 4) * 8;

  const f16* ap  = X + (size_t)(m0 + idx16) * H_INP + kofs;
  const f16* bp0 = W + (size_t)(n0 + idx16) * H_INP + kofs;

  f32x4 acc[4] = { {0,0,0,0}, {0,0,0,0}, {0,0,0,0}, {0,0,0,0} };
#pragma unroll
  for (int kt = 0; kt < 8; ++kt) {
    f16x8 a = *(const f16x8*)(ap + kt * 32);
#pragma unroll
    for (int nt = 0; nt < 4; ++nt) {
      f16x8 bb = *(const f16x8*)(bp0 + (size_t)nt * 16 * H_INP + kt * 32);
      acc[nt] = __builtin_amdgcn_mfma_f32_16x16x32_f16(a, bb, acc[nt], 0, 0, 0);
    }
  }
  const int mbase = m0 + (lane >> 4) * 4;
#pragma unroll
  for (int nt = 0; nt < 4; ++nt) {
    const int col = n0 + nt * 16 + idx16;
    const float bv = bias[col];
#pragma unroll
    for (int r = 0; r < 4; ++r)
      GI[(size_t)(mbase + r) * G3 + col] = (f16)(acc[nt][r] + bv);
  }
}

// -------------------------------------------------- GRU scan, 1 column / block
// 768 threads = 12 waves. Matvec gh = W_hh·h via MFMA 16x16x32 (M padded to
// 16, only row 0 real). Wave w owns output rows [w*64, w*64+64): 4 n-tiles x
// 8 k-chunks of B-fragments resident in registers (128 regs/lane; MFMA can
// source B from AGPR directly -> no accvgpr copies). GI rows / inv / out rows
// are staged in LDS per 16-step chunk so steady-state steps have ZERO global
// memory ops (no vmcnt drain at __syncthreads).
__global__ __launch_bounds__(768) void k_scan(const f16* __restrict__ Whh,
                                              const f16* __restrict__ GI,
                                              const float* __restrict__ h0,
                                              const float* __restrict__ bhh,
                                              const unsigned short* __restrict__ tidx,
                                              const int* __restrict__ lens,
                                              const int* __restrict__ inv,
                                              const int* __restrict__ ntru,
                                              float* __restrict__ out) {
  const int b = blockIdx.x;
  const int tid = threadIdx.x;
  const int lane = tid & 63;
  const int wav = tid >> 6;

  __shared__ f16   GIbuf[SCH * G3];      // 24576 B
  __shared__ float outb[SCH * H_HID];    // 16384 B
  __shared__ float ghs[G3];              //  3072 B
  __shared__ f16   hpk[H_HID];           //   512 B
  __shared__ int   ivb[2][SCH];          //   128 B

  // B fragments: row n = wav*64 + nt*16 + (lane&15), k = kc*32 + (lane>>4)*8 + j
  f16x8 bf[4][8];
  {
    const f16* wbase = Whh + (size_t)(wav * 64 + (lane & 15)) * H_HID + ((lane >> 4) << 3);
#pragma unroll
    for (int nt = 0; nt < 4; ++nt)
#pragma unroll
      for (int kc = 0; kc < 8; ++kc)
        bf[nt][kc] = *(const f16x8*)(wbase + (size_t)nt * 16 * H_HID + kc * 32);
  }
  float br = 0.f, bz = 0.f, bn = 0.f, h_reg = 0.f;
  if (tid < H_HID) {
    br = bhh[tid]; bz = bhh[H_HID + tid]; bn = bhh[2 * H_HID + tid];
    h_reg = h0[b * H_HID + tid];
  }
  if (tid < H_HID / 2) {
    float2 hv = ((const float2*)(h0 + b * H_HID))[tid];
    f16x2 p; p.x = (f16)hv.x; p.y = (f16)hv.y;
    ((f16x2*)hpk)[tid] = p;
  }
  const int L  = lens[b];
  const int Nt = ntru[0];
  const unsigned short* tptr = tidx + b * T_LEN;
  const bool arow = (lane & 15) == 0;   // lanes holding the real A row (m=0)
  const int  q = lane >> 4;

  for (int k = 0; k < L; ++k) {
    if ((k & (SCH - 1)) == 0) {
      const int par = (k >> 4) & 1;
      if (k > 0) {  // flush previous chunk's output rows
        for (int r = wav; r < SCH; r += 12) {
          int iv = ivb[par ^ 1][r];
          if (iv >= 0)
            *(float4*)(out + (size_t)iv * H_HID + (lane << 2)) =
                *(const float4*)(outb + r * H_HID + (lane << 2));
        }
      }
      {  // refill GI chunk + inv
        int nrows = L - k; if (nrows > SCH) nrows = SCH;
        int r = tid / 48, c = tid % 48;   // 16 rows x 48 chunks of 32 B
        if (r < nrows) {
          int t = tptr[k + r];
          const uint4* src = (const uint4*)(GI + ((size_t)t * B_N + b) * G3) + (c << 1);
          uint4 v0 = src[0], v1 = src[1];
          uint4* dst = (uint4*)(GIbuf + r * G3) + (c << 1);
          dst[0] = v0; dst[1] = v1;
        }
        if (tid < SCH) {
          int kk = k + tid;
          int pr = kk * B_N + b;
          ivb[par][tid] = (kk < L && pr < Nt) ? inv[pr] : -1;
        }
      }
      __syncthreads();
    }
    // --- matvec: gh = W_hh * h (MFMA, M=16 padded, row 0 real) ---
    {
      const f32x4 z4 = {0.f, 0.f, 0.f, 0.f};
      f16x8 af = {0, 0, 0, 0, 0, 0, 0, 0};
      if (arow) af = *(const f16x8*)(hpk + (q << 3));
      f32x4 a0 = __builtin_amdgcn_mfma_f32_16x16x32_f16(af, bf[0][0], z4, 0, 0, 0);
      f32x4 a1 = __builtin_amdgcn_mfma_f32_16x16x32_f16(af, bf[1][0], z4, 0, 0, 0);
      f32x4 a2 = __builtin_amdgcn_mfma_f32_16x16x32_f16(af, bf[2][0], z4, 0, 0, 0);
      f32x4 a3 = __builtin_amdgcn_mfma_f32_16x16x32_f16(af, bf[3][0], z4, 0, 0, 0);
#pragma unroll
      for (int kc = 1; kc < 8; ++kc) {
        f16x8 a = {0, 0, 0, 0, 0, 0, 0, 0};
        if (arow) a = *(const f16x8*)(hpk + kc * 32 + (q << 3));
        a0 = __builtin_amdgcn_mfma_f32_16x16x32_f16(a, bf[0][kc], a0, 0, 0, 0);
        a1 = __builtin_amdgcn_mfma_f32_16x16x32_f16(a, bf[1][kc], a1, 0, 0, 0);
        a2 = __builtin_amdgcn_mfma_f32_16x16x32_f16(a, bf[2][kc], a2, 0, 0, 0);
        a3 = __builtin_amdgcn_mfma_f32_16x16x32_f16(a, bf[3][kc], a3, 0, 0, 0);
      }
      // D row 0 lives in lanes 0..15, reg 0 (same mapping as verified k_gemm)
      if (lane < 16) {
        float* g = ghs + wav * 64 + lane;
        g[0]  = a0[0];
        g[16] = a1[0];
        g[32] = a2[0];
        g[48] = a3[0];
      }
    }
    __syncthreads();
    // --- gates (threads 0..255) ---
    if (tid < H_HID) {
      const int slot = k & (SCH - 1);
      const float gi0 = (float)GIbuf[slot * G3 + tid];
      const float gi1 = (float)GIbuf[slot * G3 + H_HID + tid];
      const float gi2 = (float)GIbuf[slot * G3 + 2 * H_HID + tid];
      const float ghr = ghs[tid] + br;
      const float ghz = ghs[H_HID + tid] + bz;
      const float ghn = ghs[2 * H_HID + tid] + bn;
      const float rg = __builtin_amdgcn_rcpf(1.f + __expf(-(gi0 + ghr)));
      const float zg = __builtin_amdgcn_rcpf(1.f + __expf(-(gi1 + ghz)));
      const float xx = gi2 + rg * ghn;
      const float ng = 1.f - 2.f * __builtin_amdgcn_rcpf(1.f + __expf(2.f * xx));
      const float hn = (1.f - zg) * ng + zg * h_reg;
      h_reg = hn;
      hpk[tid] = (f16)hn;
      outb[slot * H_HID + tid] = hn;
    }
    __syncthreads();
  }
  if (L > 0) {  // tail flush
    const int kb = (L - 1) & ~(SCH - 1);
    const int rows = L - kb;
    const int par = (kb >> 4) & 1;
    for (int r = wav; r < rows; r += 12) {
      int iv = ivb[par][r];
      if (iv >= 0)
        *(float4*)(out + (size_t)iv * H_HID + (lane << 2)) =
            *(const float4*)(outb + r * H_HID + (lane << 2));
    }
  }
  if (tid < H_HID)
    out[(size_t)M_ROWS * H_HID + (size_t)b * H_HID + tid] = h_reg;
}

// ---------------------------------------------------------------------------
extern "C" void kernel_launch(void* const* d_in, const int* in_sizes, int n_in,
                              void* d_out, int out_size, void* d_ws, size_t ws_size,
                              hipStream_t stream) {
  const float* x    = (const float*)d_in[0];
  const float* h0   = (const float*)d_in[1];
  const int*   mask = (const int*)d_in[2];
  const float* wih  = (const float*)d_in[3];
  const float* whh  = (const float*)d_in[4];
  const float* bih  = (const float*)d_in[5];
  const float* bhh  = (const float*)d_in[6];
  float* out = (float*)d_out;

  // workspace layout (same footprint as round 1: ~270.3 MB)
  char* ws = (char*)d_ws;
  f16* X16   = (f16*)(ws + 0);                       //  67,108,864 B
  f16* Wih16 = (f16*)(ws + 67108864);                //     393,216 B
  f16* Whh16 = (f16*)(ws + 67502080);                //     393,216 B
  f16* GI    = (f16*)(ws + 67895296);                // 201,326,592 B
  unsigned short* tidx = (unsigned short*)(ws + 269221888);  // 262,144 B
  int* rowcnt  = (int*)(ws + 269484032);             //       8,192 B
  int* rowpref = (int*)(ws + 269492224);             //       8,192 B
  int* inv   = (int*)(ws + 269746176);               //     524,288 B
  int* lens  = (int*)(ws + 270270464);               //         256 B
  int* ntru  = (int*)(ws + 270270720);               //           4 B

  hipLaunchKernelGGL(k_zero, dim3(4096), dim3(256), 0, stream,
                     (float4*)d_out, out_size / 4);
  hipLaunchKernelGGL(k_cvt, dim3(4096), dim3(256), 0, stream,
                     (const float2*)x, (f16x2*)X16, M_ROWS * H_INP / 2);
  hipLaunchKernelGGL(k_cvt, dim3(96), dim3(256), 0, stream,
                     (const float2*)wih, (f16x2*)Wih16, G3 * H_INP / 2);
  hipLaunchKernelGGL(k_cvt, dim3(96), dim3(256), 0, stream,
                     (const float2*)whh, (f16x2*)Whh16, G3 * H_INP / 2);
  hipLaunchKernelGGL(k_prep_col, dim3(B_N), dim3(64), 0, stream,
                     mask, tidx, lens);
  hipLaunchKernelGGL(k_rowcnt, dim3(512), dim3(256), 0, stream, mask, rowcnt);
  hipLaunchKernelGGL(k_rowpref, dim3(1), dim3(512), 0, stream,
                     rowcnt, rowpref, ntru);
  hipLaunchKernelGGL(k_inv, dim3(512), dim3(256), 0, stream,
                     mask, rowpref, inv);
  hipLaunchKernelGGL(k_gemm, dim3(M_ROWS / 64, G3 / 64), dim3(256), 0, stream,
                     X16, Wih16, bih, GI);
  hipLaunchKernelGGL(k_scan, dim3(B_N), dim3(768), 0, stream,
                     Whh16, GI, h0, bhh, tidx, lens, inv, ntru, out);
}